// Round 1
// baseline (52.338 us; speedup 1.0000x reference)
//
#include <hip/hip_runtime.h>

#define NB 4
#define NV 256
#define NF 256
#define IMG 128

// per-face constant block: 32 floats (128 B)
//  0- 8: A0,B0,C0, A1,B1,C1, A2,B2,C2   (barycentric affine coeffs)
//  9-14: a0x,a0y, a1x,a1y, a2x,a2y      (vertex 2D positions)
// 15-20: e01x,e01y, e12x,e12y, e20x,e20y (edge vectors)
// 21-23: ib01, ib12, ib20               (1/(|e|^2+1e-12))
// 24-26: z0,z1,z2                        (ndc z)
// 27-29: cr,cg,cb                        (face color)
// 30-31: pad

__device__ __forceinline__ float rcpf(float x) { return __builtin_amdgcn_rcpf(x); }
__device__ __forceinline__ float clamp01(float x) { return fminf(fmaxf(x, 0.0f), 1.0f); }

__global__ void prep_faces(const float* __restrict__ verts,
                           const int* __restrict__ faces,
                           const float* __restrict__ colors,
                           const float* __restrict__ eye,
                           float* __restrict__ fd)
{
    int gid = blockIdx.x * blockDim.x + threadIdx.x;
    if (gid >= NB * NF) return;
    int b = gid >> 8;
    int f = gid & 255;

    const float fpj = 1.7320508075688772f;   // 1/tan(30deg)
    const float p22 = -1.0202020202020203f;  // (far+near)/(near-far)
    const float p23 = -0.20202020202020202f; // 2*far*near/(near-far)

    // camera basis (redundant per thread; trivial cost)
    float ex = eye[b*3+0], ey = eye[b*3+1], ez = eye[b*3+2];
    float en  = sqrtf(ex*ex + ey*ey + ez*ez);
    float izn = 1.0f / (en + 1e-8f);
    float zx = ex*izn, zy = ey*izn, zz = ez*izn;
    // x = normalize(cross(up=(0,1,0), z)) = normalize((zz, 0, -zx))
    float cn  = sqrtf(zz*zz + zx*zx);
    float ixn = 1.0f / (cn + 1e-8f);
    float xx = zz*ixn, xy = 0.0f, xz = -zx*ixn;
    // y = cross(z, x)
    float yx = zy*xz - zz*xy;
    float yy = zz*xx - zx*xz;
    float yz = zx*xy - zy*xx;
    float tx = -(xx*ex + xy*ey + xz*ez);
    float ty = -(yx*ex + yy*ey + yz*ez);
    float tz = -(zx*ex + zy*ey + zz*ez);

    int i0 = faces[f*3+0], i1 = faces[f*3+1], i2 = faces[f*3+2];
    int idx[3] = { i0, i1, i2 };

    float ax[3], ay[3], az[3];
#pragma unroll
    for (int k = 0; k < 3; ++k) {
        const float* v = verts + (b*NV + idx[k])*3;
        float vx = v[0], vy = v[1], vz = v[2];
        float cx  = fpj*(xx*vx + xy*vy + xz*vz + tx);
        float cyv = fpj*(yx*vx + yy*vy + yz*vz + ty);
        float zv  = zx*vx + zy*vy + zz*vz + tz;
        float cz  = p22*zv + p23;
        float cw  = -zv;
        float iw  = 1.0f / (cw + 1e-8f);
        ax[k] = cx*iw; ay[k] = cyv*iw; az[k] = cz*iw;
    }

    float a0x = ax[0], a0y = ay[0];
    float a1x = ax[1], a1y = ay[1];
    float a2x = ax[2], a2y = ay[2];

    float e01x = a1x - a0x, e01y = a1y - a0y;
    float e12x = a2x - a1x, e12y = a2y - a1y;
    float e20x = a0x - a2x, e20y = a0y - a2y;

    float area  = e01x*(a2y - a0y) - e01y*(a2x - a0x);
    float denom = area + (area >= 0.0f ? 1e-12f : -1e-12f);
    float idn   = 1.0f / denom;

    // w0 = cross2(e12, p-a1); w1 = cross2(e20, p-a2); w2 = cross2(e01, p-a0)
    float A0 = -e12y*idn, B0 = e12x*idn, C0 = (e12y*a1x - e12x*a1y)*idn;
    float A1 = -e20y*idn, B1 = e20x*idn, C1 = (e20y*a2x - e20x*a2y)*idn;
    float A2 = -e01y*idn, B2 = e01x*idn, C2 = (e01y*a0x - e01x*a0y)*idn;

    float ib01 = 1.0f / (e01x*e01x + e01y*e01y + 1e-12f);
    float ib12 = 1.0f / (e12x*e12x + e12y*e12y + 1e-12f);
    float ib20 = 1.0f / (e20x*e20x + e20y*e20y + 1e-12f);

    const float third = (1.0f/3.0f);
    float cr = (colors[(b*NV+i0)*3+0] + colors[(b*NV+i1)*3+0] + colors[(b*NV+i2)*3+0]) * third;
    float cg = (colors[(b*NV+i0)*3+1] + colors[(b*NV+i1)*3+1] + colors[(b*NV+i2)*3+1]) * third;
    float cb = (colors[(b*NV+i0)*3+2] + colors[(b*NV+i1)*3+2] + colors[(b*NV+i2)*3+2]) * third;

    float* o = fd + gid*32;
    o[0]=A0;  o[1]=B0;  o[2]=C0;
    o[3]=A1;  o[4]=B1;  o[5]=C1;
    o[6]=A2;  o[7]=B2;  o[8]=C2;
    o[9]=a0x; o[10]=a0y; o[11]=a1x; o[12]=a1y; o[13]=a2x; o[14]=a2y;
    o[15]=e01x; o[16]=e01y; o[17]=e12x; o[18]=e12y; o[19]=e20x; o[20]=e20y;
    o[21]=ib01; o[22]=ib12; o[23]=ib20;
    o[24]=az[0]; o[25]=az[1]; o[26]=az[2];
    o[27]=cr; o[28]=cg; o[29]=cb;
    o[30]=0.0f; o[31]=0.0f;
}

// block = (64,4): threadIdx.x = pixel-in-group, threadIdx.y = face chunk (64 faces each)
// grid = 1024: blockIdx.x = b*256 + pixel-group
__launch_bounds__(256)
__global__ void raster(const float* __restrict__ fd, float* __restrict__ out)
{
    __shared__ float sP[4][64], sM[4][64], sS[4][64];
    __shared__ float sR0[4][64], sR1[4][64], sR2[4][64];

    const int t   = threadIdx.x;       // 0..63
    const int cy  = threadIdx.y;       // 0..3 (face chunk)
    const int b   = blockIdx.x >> 8;   // uniform (from blockIdx only!)
    const int grp = blockIdx.x & 255;
    const int pixb = grp*64 + t;       // pixel within batch image
    const int h = pixb >> 7;
    const int w = pixb & 127;

    const float px = (w + 0.5f) * (1.0f/64.0f) - 1.0f;
    const float py = 1.0f - (h + 0.5f) * (1.0f/64.0f);

    // wave-uniform face-data base -> scalar loads
    int foff = ((b << 8) + (cy << 6)) * 32;
    foff = __builtin_amdgcn_readfirstlane(foff);
    const float* fc = fd + foff;

    const float INV_SIGMA = 1.0e4f;  // 1/SIGMA
    const float INV_GAMMA = 10.0f;   // 1/GAMMA

    float prod = 1.0f;   // prod(1-prob)
    float m = 0.0f;      // running max of zn (zn >= 0 always)
    float S = 0.0f;
    float R0 = 0.0f, R1 = 0.0f, R2 = 0.0f;

#pragma unroll 2
    for (int i = 0; i < 64; ++i) {
        const float* c = fc + i*32;
        float A0=c[0], B0=c[1], C0=c[2];
        float A1=c[3], B1=c[4], C1=c[5];
        float A2=c[6], B2=c[7], C2=c[8];
        float a0x=c[9],  a0y=c[10], a1x=c[11], a1y=c[12], a2x=c[13], a2y=c[14];
        float e01x=c[15], e01y=c[16], e12x=c[17], e12y=c[18], e20x=c[19], e20y=c[20];
        float ib01=c[21], ib12=c[22], ib20=c[23];
        float z0=c[24], z1=c[25], z2=c[26];
        float cr=c[27], cg=c[28], cb=c[29];

        float b0 = A0*px + B0*py + C0;
        float b1 = A1*px + B1*py + C1;
        float b2 = A2*px + B2*py + C2;
        bool inside = (b0 >= 0.0f) & (b1 >= 0.0f) & (b2 >= 0.0f);

        // point-segment squared distances (sqrt elided: only d*d is used)
        float pax = px - a0x, pay = py - a0y;
        float tt  = clamp01((pax*e01x + pay*e01y) * ib01);
        float dx  = pax - tt*e01x, dy = pay - tt*e01y;
        float dd0 = dx*dx + dy*dy;

        pax = px - a1x; pay = py - a1y;
        tt  = clamp01((pax*e12x + pay*e12y) * ib12);
        dx  = pax - tt*e12x; dy = pay - tt*e12y;
        float dd1 = dx*dx + dy*dy;

        pax = px - a2x; pay = py - a2y;
        tt  = clamp01((pax*e20x + pay*e20y) * ib20);
        dx  = pax - tt*e20x; dy = pay - tt*e20y;
        float dd2 = dx*dx + dy*dy;

        float dd = fminf(dd0, fminf(dd1, dd2)) + 1e-12f;

        // prob = sigmoid(sgn * dd / SIGMA) = 1/(1+exp(-sgn*dd/SIGMA))
        float q = inside ? -dd*INV_SIGMA : dd*INV_SIGMA;
        float prob = rcpf(1.0f + __expf(q));   // exp(+huge)->inf -> rcp(inf)=0, ok

        prod = prod - prob*prod;               // prod *= (1 - prob)

        // z at pixel from clamped barycentrics
        float bc0 = clamp01(b0), bc1 = clamp01(b1), bc2 = clamp01(b2);
        float s  = bc0 + bc1 + bc2 + 1e-8f;
        float zp = (bc0*z0 + bc1*z1 + bc2*z2) * rcpf(s);
        float zn = clamp01(0.5f - 0.5f*zp);

        // online softmax over faces (exp((zn-m)/GAMMA) weights)
        float nm    = fmaxf(m, zn);
        float alpha = __expf((m - nm) * INV_GAMMA);
        float wgt   = prob * __expf((zn - nm) * INV_GAMMA);
        S  = S*alpha  + wgt;
        R0 = R0*alpha + wgt*cr;
        R1 = R1*alpha + wgt*cg;
        R2 = R2*alpha + wgt*cb;
        m  = nm;
    }

    sP[cy][t] = prod; sM[cy][t] = m; sS[cy][t] = S;
    sR0[cy][t] = R0;  sR1[cy][t] = R1; sR2[cy][t] = R2;
    __syncthreads();

    if (cy == 0) {
        float P = sP[0][t] * sP[1][t] * sP[2][t] * sP[3][t];
        float M = fmaxf(fmaxf(sM[0][t], sM[1][t]), fmaxf(sM[2][t], sM[3][t]));
        float St = 0.0f, r0 = 0.0f, r1 = 0.0f, r2 = 0.0f;
#pragma unroll
        for (int c2 = 0; c2 < 4; ++c2) {
            float al = __expf((sM[c2][t] - M) * 10.0f);
            St += sS[c2][t] * al;
            r0 += sR0[c2][t] * al;
            r1 += sR1[c2][t] * al;
            r2 += sR2[c2][t] * al;
        }
        float wbg  = __expf(-M * 10.0f);
        float iden = rcpf(St + wbg);

        out[b*16384 + pixb] = 1.0f - P;                 // sil (B,1,H,W)
        float* rgb = out + 65536;                       // rgb (B,3,H,W)
        rgb[(b*3 + 0)*16384 + pixb] = r0 * iden;
        rgb[(b*3 + 1)*16384 + pixb] = r1 * iden;
        rgb[(b*3 + 2)*16384 + pixb] = r2 * iden;
    }
}

extern "C" void kernel_launch(void* const* d_in, const int* in_sizes, int n_in,
                              void* d_out, int out_size, void* d_ws, size_t ws_size,
                              hipStream_t stream)
{
    const float* verts  = (const float*)d_in[0];
    const int*   faces  = (const int*)d_in[1];
    const float* colors = (const float*)d_in[2];
    const float* eye    = (const float*)d_in[3];
    float* out = (float*)d_out;
    float* fd  = (float*)d_ws;  // 1024 faces * 32 floats = 128 KB

    hipLaunchKernelGGL(prep_faces, dim3(4), dim3(256), 0, stream,
                       verts, faces, colors, eye, fd);
    hipLaunchKernelGGL(raster, dim3(1024), dim3(64, 4), 0, stream, fd, out);
}

// Round 2
// 48.329 us; speedup vs baseline: 1.0830x; 1.0830x over previous
//
#include <hip/hip_runtime.h>

#define NB 4
#define NV 256
#define NF 256
#define IMG 128

// per-face constant block: 32 floats (128 B) — see prep_faces for layout

__device__ __forceinline__ float rcpf(float x) { return __builtin_amdgcn_rcpf(x); }
__device__ __forceinline__ float clamp01(float x) { return fminf(fmaxf(x, 0.0f), 1.0f); }

__global__ void prep_faces(const float* __restrict__ verts,
                           const int* __restrict__ faces,
                           const float* __restrict__ colors,
                           const float* __restrict__ eye,
                           float* __restrict__ fd)
{
    int gid = blockIdx.x * blockDim.x + threadIdx.x;
    if (gid >= NB * NF) return;
    int b = gid >> 8;
    int f = gid & 255;

    const float fpj = 1.7320508075688772f;   // 1/tan(30deg)
    const float p22 = -1.0202020202020203f;  // (far+near)/(near-far)
    const float p23 = -0.20202020202020202f; // 2*far*near/(near-far)

    float ex = eye[b*3+0], ey = eye[b*3+1], ez = eye[b*3+2];
    float en  = sqrtf(ex*ex + ey*ey + ez*ez);
    float izn = 1.0f / (en + 1e-8f);
    float zx = ex*izn, zy = ey*izn, zz = ez*izn;
    float cn  = sqrtf(zz*zz + zx*zx);
    float ixn = 1.0f / (cn + 1e-8f);
    float xx = zz*ixn, xy = 0.0f, xz = -zx*ixn;
    float yx = zy*xz - zz*xy;
    float yy = zz*xx - zx*xz;
    float yz = zx*xy - zy*xx;
    float tx = -(xx*ex + xy*ey + xz*ez);
    float ty = -(yx*ex + yy*ey + yz*ez);
    float tz = -(zx*ex + zy*ey + zz*ez);

    int i0 = faces[f*3+0], i1 = faces[f*3+1], i2 = faces[f*3+2];
    int idx[3] = { i0, i1, i2 };

    float ax[3], ay[3], az[3];
#pragma unroll
    for (int k = 0; k < 3; ++k) {
        const float* v = verts + (b*NV + idx[k])*3;
        float vx = v[0], vy = v[1], vz = v[2];
        float cx  = fpj*(xx*vx + xy*vy + xz*vz + tx);
        float cyv = fpj*(yx*vx + yy*vy + yz*vz + ty);
        float zv  = zx*vx + zy*vy + zz*vz + tz;
        float cz  = p22*zv + p23;
        float cw  = -zv;
        float iw  = 1.0f / (cw + 1e-8f);
        ax[k] = cx*iw; ay[k] = cyv*iw; az[k] = cz*iw;
    }

    float a0x = ax[0], a0y = ay[0];
    float a1x = ax[1], a1y = ay[1];
    float a2x = ax[2], a2y = ay[2];

    float e01x = a1x - a0x, e01y = a1y - a0y;
    float e12x = a2x - a1x, e12y = a2y - a1y;
    float e20x = a0x - a2x, e20y = a0y - a2y;

    float area  = e01x*(a2y - a0y) - e01y*(a2x - a0x);
    float denom = area + (area >= 0.0f ? 1e-12f : -1e-12f);
    float idn   = 1.0f / denom;

    float A0 = -e12y*idn, B0 = e12x*idn, C0 = (e12y*a1x - e12x*a1y)*idn;
    float A1 = -e20y*idn, B1 = e20x*idn, C1 = (e20y*a2x - e20x*a2y)*idn;
    float A2 = -e01y*idn, B2 = e01x*idn, C2 = (e01y*a0x - e01x*a0y)*idn;

    float ib01 = 1.0f / (e01x*e01x + e01y*e01y + 1e-12f);
    float ib12 = 1.0f / (e12x*e12x + e12y*e12y + 1e-12f);
    float ib20 = 1.0f / (e20x*e20x + e20y*e20y + 1e-12f);

    const float third = (1.0f/3.0f);
    float cr = (colors[(b*NV+i0)*3+0] + colors[(b*NV+i1)*3+0] + colors[(b*NV+i2)*3+0]) * third;
    float cg = (colors[(b*NV+i0)*3+1] + colors[(b*NV+i1)*3+1] + colors[(b*NV+i2)*3+1]) * third;
    float cb = (colors[(b*NV+i0)*3+2] + colors[(b*NV+i1)*3+2] + colors[(b*NV+i2)*3+2]) * third;

    float* o = fd + gid*32;
    o[0]=A0;  o[1]=B0;  o[2]=C0;
    o[3]=A1;  o[4]=B1;  o[5]=C1;
    o[6]=A2;  o[7]=B2;  o[8]=C2;
    o[9]=a0x; o[10]=a0y; o[11]=a1x; o[12]=a1y; o[13]=a2x; o[14]=a2y;
    o[15]=e01x; o[16]=e01y; o[17]=e12x; o[18]=e12y; o[19]=e20x; o[20]=e20y;
    o[21]=ib01; o[22]=ib12; o[23]=ib20;
    o[24]=az[0]; o[25]=az[1]; o[26]=az[2];
    o[27]=cr; o[28]=cg; o[29]=cb;
    o[30]=0.0f; o[31]=0.0f;
}

// block = (64,8): threadIdx.x = pixel lane, threadIdx.y = face chunk (32 faces)
// grid = 1024: blockIdx.x = b*256 + pixel-group
__launch_bounds__(512)
__global__ void raster(const float* __restrict__ fd, float* __restrict__ out)
{
    __shared__ float sP[8][64], sS[8][64];
    __shared__ float sR0[8][64], sR1[8][64], sR2[8][64];

    const int t   = threadIdx.x;       // 0..63
    const int cy  = threadIdx.y;       // 0..7 (face chunk)
    const int b   = blockIdx.x >> 8;   // wave-uniform (from blockIdx only)
    const int grp = blockIdx.x & 255;
    const int pixb = grp*64 + t;       // pixel within batch image
    const int h = pixb >> 7;
    const int w = pixb & 127;

    const float px = (w + 0.5f) * (1.0f/64.0f) - 1.0f;
    const float py = 1.0f - (h + 0.5f) * (1.0f/64.0f);

    // wave-uniform face-data base -> scalar loads
    int foff = ((b << 8) + (cy << 5)) * 32;
    foff = __builtin_amdgcn_readfirstlane(foff);
    const float* fc = fd + foff;

    // constants with log2(e) pre-folded (use exp2 directly)
    const float KSIG = 14426.950408889634f;  // (1/SIGMA) * log2(e)
    const float KGAM = 14.426950408889634f;  // (1/GAMMA) * log2(e)

    float prod = 1.0f;   // prod(1-prob)
    float S = 0.0f;      // sum of absolute weights (bg weight = exp2(0) = 1)
    float R0 = 0.0f, R1 = 0.0f, R2 = 0.0f;

#pragma unroll 4
    for (int i = 0; i < 32; ++i) {
        const float* c = fc + i*32;
        float A0=c[0], B0=c[1], C0=c[2];
        float A1=c[3], B1=c[4], C1=c[5];
        float A2=c[6], B2=c[7], C2=c[8];
        float a0x=c[9],  a0y=c[10], a1x=c[11], a1y=c[12], a2x=c[13], a2y=c[14];
        float e01x=c[15], e01y=c[16], e12x=c[17], e12y=c[18], e20x=c[19], e20y=c[20];
        float ib01=c[21], ib12=c[22], ib20=c[23];
        float z0=c[24], z1=c[25], z2=c[26];
        float cr=c[27], cg=c[28], cb=c[29];

        float b0 = A0*px + B0*py + C0;
        float b1 = A1*px + B1*py + C1;
        float b2 = A2*px + B2*py + C2;
        bool inside = (b0 >= 0.0f) & (b1 >= 0.0f) & (b2 >= 0.0f);

        // point-segment squared distances (sqrt elided: only d*d is used)
        float pax = px - a0x, pay = py - a0y;
        float tt  = clamp01((pax*e01x + pay*e01y) * ib01);
        float dx  = pax - tt*e01x, dy = pay - tt*e01y;
        float dd0 = dx*dx + dy*dy;

        pax = px - a1x; pay = py - a1y;
        tt  = clamp01((pax*e12x + pay*e12y) * ib12);
        dx  = pax - tt*e12x; dy = pay - tt*e12y;
        float dd1 = dx*dx + dy*dy;

        pax = px - a2x; pay = py - a2y;
        tt  = clamp01((pax*e20x + pay*e20y) * ib20);
        dx  = pax - tt*e20x; dy = pay - tt*e20y;
        float dd2 = dx*dx + dy*dy;

        float dd = fminf(dd0, fminf(dd1, dd2)) + 1e-12f;

        // prob = sigmoid(sgn*dd/SIGMA) = 1/(1+exp2(-sgn*dd*KSIG))
        float q = inside ? -dd*KSIG : dd*KSIG;
        float prob = rcpf(1.0f + exp2f(q));   // exp2(+huge)->inf -> rcp(inf)=0, ok

        prod = prod - prob*prod;              // prod *= (1 - prob)

        // z at pixel from clamped barycentrics
        float bc0 = clamp01(b0), bc1 = clamp01(b1), bc2 = clamp01(b2);
        float s  = bc0 + bc1 + bc2 + 1e-8f;
        float zp = (bc0*z0 + bc1*z1 + bc2*z2) * rcpf(s);
        float zn = clamp01(0.5f - 0.5f*zp);

        // absolute softmax weight: zn in [0,1] -> exp2(zn*KGAM) <= 2.2e4, no max needed
        float wgt = prob * exp2f(zn * KGAM);
        S  += wgt;
        R0 += wgt*cr;
        R1 += wgt*cg;
        R2 += wgt*cb;
    }

    sP[cy][t] = prod; sS[cy][t] = S;
    sR0[cy][t] = R0;  sR1[cy][t] = R1; sR2[cy][t] = R2;
    __syncthreads();

    if (cy == 0) {
        float P  = 1.0f, St = 0.0f, r0 = 0.0f, r1 = 0.0f, r2 = 0.0f;
#pragma unroll
        for (int c2 = 0; c2 < 8; ++c2) {
            P  *= sP[c2][t];
            St += sS[c2][t];
            r0 += sR0[c2][t];
            r1 += sR1[c2][t];
            r2 += sR2[c2][t];
        }
        float iden = rcpf(St + 1.0f);         // background weight = exp2(0) = 1

        out[b*16384 + pixb] = 1.0f - P;       // sil (B,1,H,W)
        float* rgb = out + 65536;             // rgb (B,3,H,W)
        rgb[(b*3 + 0)*16384 + pixb] = r0 * iden;
        rgb[(b*3 + 1)*16384 + pixb] = r1 * iden;
        rgb[(b*3 + 2)*16384 + pixb] = r2 * iden;
    }
}

extern "C" void kernel_launch(void* const* d_in, const int* in_sizes, int n_in,
                              void* d_out, int out_size, void* d_ws, size_t ws_size,
                              hipStream_t stream)
{
    const float* verts  = (const float*)d_in[0];
    const int*   faces  = (const int*)d_in[1];
    const float* colors = (const float*)d_in[2];
    const float* eye    = (const float*)d_in[3];
    float* out = (float*)d_out;
    float* fd  = (float*)d_ws;  // 1024 faces * 32 floats = 128 KB

    hipLaunchKernelGGL(prep_faces, dim3(4), dim3(256), 0, stream,
                       verts, faces, colors, eye, fd);
    hipLaunchKernelGGL(raster, dim3(1024), dim3(64, 8), 0, stream, fd, out);
}

// Round 3
// 37.848 us; speedup vs baseline: 1.3829x; 1.2769x over previous
//
#include <hip/hip_runtime.h>

#define NB 4
#define NV 256
#define NF 256
#define IMG 128
#define STRIDE 60   // floats per face-PAIR block (29 slots x 2, padded)

typedef float v2f __attribute__((ext_vector_type(2)));

__device__ __forceinline__ float rcpf(float x) { return __builtin_amdgcn_rcpf(x); }
__device__ __forceinline__ float med01(float x) { return __builtin_amdgcn_fmed3f(x, 0.0f, 1.0f); }
__device__ __forceinline__ v2f fma2(v2f a, v2f b, v2f c) { return __builtin_elementwise_fma(a, b, c); }

// slot layout (pair-interleaved: value k of face f at [2k + (f&1)]):
//  0 A0  1 B0  2 C0  3 A1  4 B1  5 C1  6 A2  7 B2  8 C2
//  9 a0x 10 a0y
// 11 e01x 12 e01y 13 e12x 14 e12y 15 e20x 16 e20y
// 17 g01x 18 g01y 19 g12x 20 g12y 21 g20x 22 g20y   (g = e / (|e|^2+1e-12))
// 23 z0 24 z1 25 z2  26 cr 27 cg 28 cb

__global__ void prep_faces(const float* __restrict__ verts,
                           const int* __restrict__ faces,
                           const float* __restrict__ colors,
                           const float* __restrict__ eye,
                           float* __restrict__ fd)
{
    int gid = blockIdx.x * blockDim.x + threadIdx.x;
    if (gid >= NB * NF) return;
    int b = gid >> 8;
    int f = gid & 255;

    const float fpj = 1.7320508075688772f;   // 1/tan(30deg)
    const float p22 = -1.0202020202020203f;  // (far+near)/(near-far)
    const float p23 = -0.20202020202020202f; // 2*far*near/(near-far)

    float ex = eye[b*3+0], ey = eye[b*3+1], ez = eye[b*3+2];
    float en  = sqrtf(ex*ex + ey*ey + ez*ez);
    float izn = 1.0f / (en + 1e-8f);
    float zx = ex*izn, zy = ey*izn, zz = ez*izn;
    float cn  = sqrtf(zz*zz + zx*zx);
    float ixn = 1.0f / (cn + 1e-8f);
    float xx = zz*ixn, xy = 0.0f, xz = -zx*ixn;
    float yx = zy*xz - zz*xy;
    float yy = zz*xx - zx*xz;
    float yz = zx*xy - zy*xx;
    float tx = -(xx*ex + xy*ey + xz*ez);
    float ty = -(yx*ex + yy*ey + yz*ez);
    float tz = -(zx*ex + zy*ey + zz*ez);

    int i0 = faces[f*3+0], i1 = faces[f*3+1], i2 = faces[f*3+2];
    int idx[3] = { i0, i1, i2 };

    float ax[3], ay[3], az[3];
#pragma unroll
    for (int k = 0; k < 3; ++k) {
        const float* v = verts + (b*NV + idx[k])*3;
        float vx = v[0], vy = v[1], vz = v[2];
        float cx  = fpj*(xx*vx + xy*vy + xz*vz + tx);
        float cyv = fpj*(yx*vx + yy*vy + yz*vz + ty);
        float zv  = zx*vx + zy*vy + zz*vz + tz;
        float cz  = p22*zv + p23;
        float cw  = -zv;
        float iw  = 1.0f / (cw + 1e-8f);
        ax[k] = cx*iw; ay[k] = cyv*iw; az[k] = cz*iw;
    }

    float a0x = ax[0], a0y = ay[0];
    float a1x = ax[1], a1y = ay[1];
    float a2x = ax[2], a2y = ay[2];

    float e01x = a1x - a0x, e01y = a1y - a0y;
    float e12x = a2x - a1x, e12y = a2y - a1y;
    float e20x = a0x - a2x, e20y = a0y - a2y;

    float area  = e01x*(a2y - a0y) - e01y*(a2x - a0x);
    float denom = area + (area >= 0.0f ? 1e-12f : -1e-12f);
    float idn   = 1.0f / denom;

    float A0 = -e12y*idn, B0 = e12x*idn, C0 = (e12y*a1x - e12x*a1y)*idn;
    float A1 = -e20y*idn, B1 = e20x*idn, C1 = (e20y*a2x - e20x*a2y)*idn;
    float A2 = -e01y*idn, B2 = e01x*idn, C2 = (e01y*a0x - e01x*a0y)*idn;

    float ib01 = 1.0f / (e01x*e01x + e01y*e01y + 1e-12f);
    float ib12 = 1.0f / (e12x*e12x + e12y*e12y + 1e-12f);
    float ib20 = 1.0f / (e20x*e20x + e20y*e20y + 1e-12f);

    const float third = (1.0f/3.0f);
    float cr = (colors[(b*NV+i0)*3+0] + colors[(b*NV+i1)*3+0] + colors[(b*NV+i2)*3+0]) * third;
    float cg = (colors[(b*NV+i0)*3+1] + colors[(b*NV+i1)*3+1] + colors[(b*NV+i2)*3+1]) * third;
    float cb = (colors[(b*NV+i0)*3+2] + colors[(b*NV+i1)*3+2] + colors[(b*NV+i2)*3+2]) * third;

    // pair-interleaved write
    float* o = fd + (b*128 + (f >> 1))*STRIDE + (f & 1);
    o[ 0]=A0;   o[ 2]=B0;   o[ 4]=C0;
    o[ 6]=A1;   o[ 8]=B1;   o[10]=C1;
    o[12]=A2;   o[14]=B2;   o[16]=C2;
    o[18]=a0x;  o[20]=a0y;
    o[22]=e01x; o[24]=e01y; o[26]=e12x; o[28]=e12y; o[30]=e20x; o[32]=e20y;
    o[34]=e01x*ib01; o[36]=e01y*ib01;
    o[38]=e12x*ib12; o[40]=e12y*ib12;
    o[42]=e20x*ib20; o[44]=e20y*ib20;
    o[46]=az[0]; o[48]=az[1]; o[50]=az[2];
    o[52]=cr;   o[54]=cg;   o[56]=cb;
}

// block = (64,8): threadIdx.x = pixel lane, threadIdx.y = chunk of 16 face-pairs
// grid = 1024: blockIdx.x = b*256 + pixel-group
__launch_bounds__(512)
__global__ void raster(const float* __restrict__ fd, float* __restrict__ out)
{
    __shared__ float sP[8][64], sS[8][64];
    __shared__ float sR0[8][64], sR1[8][64], sR2[8][64];

    const int t   = threadIdx.x;       // 0..63
    const int cy  = threadIdx.y;       // 0..7
    const int b   = blockIdx.x >> 8;   // wave-uniform
    const int grp = blockIdx.x & 255;
    const int pixb = grp*64 + t;
    const int h = pixb >> 7;
    const int w = pixb & 127;

    const float px = (w + 0.5f) * (1.0f/64.0f) - 1.0f;
    const float py = 1.0f - (h + 0.5f) * (1.0f/64.0f);
    const v2f px2 = { px, px };
    const v2f py2 = { py, py };

    int foff = (b*128 + cy*16) * STRIDE;
    foff = __builtin_amdgcn_readfirstlane(foff);
    const float* fc = fd + foff;

    const float KSIG = 14426.950408889634f;  // (1/SIGMA)*log2(e)
    const float KGAM = 14.426950408889634f;  // (1/GAMMA)*log2(e)
    const v2f KSIG2 = { KSIG, KSIG };
    const v2f KGAM2 = { KGAM, KGAM };
    const v2f ONE2  = { 1.0f, 1.0f };
    const v2f NHALF = { -0.5f, -0.5f };
    const v2f HALF  = { 0.5f, 0.5f };
    const v2f EPS2  = { 1e-8f, 1e-8f };

    v2f prod2 = { 1.0f, 1.0f };
    v2f S2  = { 0.0f, 0.0f };
    v2f R02 = { 0.0f, 0.0f };
    v2f R12 = { 0.0f, 0.0f };
    v2f R22 = { 0.0f, 0.0f };

    for (int i = 0; i < 16; ++i) {
        const float* c = fc + i*STRIDE;
#define LD(k) (*(const v2f*)(c + 2*(k)))
        v2f A0 = LD(0),  B0 = LD(1),  C0 = LD(2);
        v2f A1 = LD(3),  B1 = LD(4),  C1 = LD(5);
        v2f A2 = LD(6),  B2 = LD(7),  C2 = LD(8);
        v2f a0x = LD(9), a0y = LD(10);
        v2f e01x = LD(11), e01y = LD(12);
        v2f e12x = LD(13), e12y = LD(14);
        v2f e20x = LD(15), e20y = LD(16);
        v2f g01x = LD(17), g01y = LD(18);
        v2f g12x = LD(19), g12y = LD(20);
        v2f g20x = LD(21), g20y = LD(22);
        v2f z0 = LD(23), z1 = LD(24), z2 = LD(25);
        v2f cr = LD(26), cg = LD(27), cb = LD(28);
#undef LD

        // barycentrics (packed, one SGPR-pair per op)
        v2f b0 = fma2(A0, px2, B0*py2) + C0;
        v2f b1 = fma2(A1, px2, B1*py2) + C1;
        v2f b2 = fma2(A2, px2, B2*py2) + C2;

        // pa vectors
        v2f pa0x = px2 - a0x, pa0y = py2 - a0y;
        v2f pa1x = pa0x - e01x, pa1y = pa0y - e01y;
        v2f pa2x = pa0x + e20x, pa2y = pa0y + e20y;

        // edge 01
        v2f tt = fma2(pa0x, g01x, pa0y*g01y);
        tt = (v2f){ med01(tt.x), med01(tt.y) };
        v2f dx = fma2(-tt, e01x, pa0x);
        v2f dy = fma2(-tt, e01y, pa0y);
        v2f dd0 = fma2(dx, dx, dy*dy);
        // edge 12
        tt = fma2(pa1x, g12x, pa1y*g12y);
        tt = (v2f){ med01(tt.x), med01(tt.y) };
        dx = fma2(-tt, e12x, pa1x);
        dy = fma2(-tt, e12y, pa1y);
        v2f dd1 = fma2(dx, dx, dy*dy);
        // edge 20
        tt = fma2(pa2x, g20x, pa2y*g20y);
        tt = (v2f){ med01(tt.x), med01(tt.y) };
        dx = fma2(-tt, e20x, pa2x);
        dy = fma2(-tt, e20y, pa2y);
        v2f dd2 = fma2(dx, dx, dy*dy);

        // min squared distance, scaled for exp2
        float ddl = fminf(fminf(dd0.x, dd1.x), dd2.x);
        float ddh = fminf(fminf(dd0.y, dd1.y), dd2.y);
        v2f ddk = ((v2f){ ddl, ddh }) * KSIG2;

        // inside test per half
        float inl = fminf(fminf(b0.x, b1.x), b2.x);
        float inh = fminf(fminf(b0.y, b1.y), b2.y);
        float qx = (inl >= 0.0f) ? -ddk.x : ddk.x;
        float qy = (inh >= 0.0f) ? -ddk.y : ddk.y;

        v2f e2 = { exp2f(qx), exp2f(qy) };
        v2f den = e2 + ONE2;
        v2f prob = { rcpf(den.x), rcpf(den.y) };

        prod2 = fma2(-prob, prod2, prod2);   // prod *= (1-prob)

        // clamped barycentrics -> z
        v2f bc0 = { med01(b0.x), med01(b0.y) };
        v2f bc1 = { med01(b1.x), med01(b1.y) };
        v2f bc2 = { med01(b2.x), med01(b2.y) };
        v2f s   = (bc0 + bc1) + (bc2 + EPS2);
        v2f zs  = fma2(bc0, z0, fma2(bc1, z1, bc2*z2));
        v2f irs = { rcpf(s.x), rcpf(s.y) };
        v2f zp  = zs * irs;
        v2f zn  = fma2(zp, NHALF, HALF);
        zn = (v2f){ med01(zn.x), med01(zn.y) };

        v2f znk = zn * KGAM2;
        v2f ez  = { exp2f(znk.x), exp2f(znk.y) };
        v2f wgt = prob * ez;

        S2  = S2 + wgt;
        R02 = fma2(wgt, cr, R02);
        R12 = fma2(wgt, cg, R12);
        R22 = fma2(wgt, cb, R22);
    }

    sP[cy][t]  = prod2.x * prod2.y;
    sS[cy][t]  = S2.x  + S2.y;
    sR0[cy][t] = R02.x + R02.y;
    sR1[cy][t] = R12.x + R12.y;
    sR2[cy][t] = R22.x + R22.y;
    __syncthreads();

    if (cy == 0) {
        float P  = 1.0f, St = 0.0f, r0 = 0.0f, r1 = 0.0f, r2 = 0.0f;
#pragma unroll
        for (int c2 = 0; c2 < 8; ++c2) {
            P  *= sP[c2][t];
            St += sS[c2][t];
            r0 += sR0[c2][t];
            r1 += sR1[c2][t];
            r2 += sR2[c2][t];
        }
        float iden = rcpf(St + 1.0f);   // background weight = exp2(0) = 1

        out[b*16384 + pixb] = 1.0f - P;
        float* rgb = out + 65536;
        rgb[(b*3 + 0)*16384 + pixb] = r0 * iden;
        rgb[(b*3 + 1)*16384 + pixb] = r1 * iden;
        rgb[(b*3 + 2)*16384 + pixb] = r2 * iden;
    }
}

extern "C" void kernel_launch(void* const* d_in, const int* in_sizes, int n_in,
                              void* d_out, int out_size, void* d_ws, size_t ws_size,
                              hipStream_t stream)
{
    const float* verts  = (const float*)d_in[0];
    const int*   faces  = (const int*)d_in[1];
    const float* colors = (const float*)d_in[2];
    const float* eye    = (const float*)d_in[3];
    float* out = (float*)d_out;
    float* fd  = (float*)d_ws;  // 4*128 pairs * 60 floats = 120 KB (< ws)

    hipLaunchKernelGGL(prep_faces, dim3(4), dim3(256), 0, stream,
                       verts, faces, colors, eye, fd);
    hipLaunchKernelGGL(raster, dim3(1024), dim3(64, 8), 0, stream, fd, out);
}

// Round 4
// 35.545 us; speedup vs baseline: 1.4724x; 1.0648x over previous
//
#include <hip/hip_runtime.h>

#define NB 4
#define NV 256
#define NF 256
#define IMG 128
#define STRIDE 64   // floats per face-PAIR block (29 slots x 2 = 58, padded to 64 -> 256B aligned)

typedef float v2f __attribute__((ext_vector_type(2)));
#define CONST_AS __attribute__((address_space(4)))

__device__ __forceinline__ float rcpf(float x) { return __builtin_amdgcn_rcpf(x); }
__device__ __forceinline__ float ex2(float x)  { return __builtin_amdgcn_exp2f(x); }
__device__ __forceinline__ float med01(float x) { return __builtin_amdgcn_fmed3f(x, 0.0f, 1.0f); }
__device__ __forceinline__ v2f med01_2(v2f v) { return (v2f){ med01(v.x), med01(v.y) }; }
__device__ __forceinline__ v2f fma2(v2f a, v2f b, v2f c) { return __builtin_elementwise_fma(a, b, c); }

// slot layout (pair-interleaved: value k of face f at [2k + (f&1)]), geometry pre-scaled by s=sqrt(KSIG):
//  0 A0  1 B0  2 C0  3 A1  4 B1  5 C1  6 A2  7 B2  8 C2      (barycentric affine, UNscaled)
//  9 a0x*s 10 a0y*s
// 11 e01x*s 12 e01y*s 13 e12x*s 14 e12y*s 15 e20x*s 16 e20y*s
// 17 g01x/s 18 g01y/s 19 g12x/s 20 g12y/s 21 g20x/s 22 g20y/s  (g = e/(|e|^2+1e-12))
// 23 z0 24 z1 25 z2  26 cr 27 cg 28 cb

__global__ void prep_faces(const float* __restrict__ verts,
                           const int* __restrict__ faces,
                           const float* __restrict__ colors,
                           const float* __restrict__ eye,
                           float* __restrict__ fd)
{
    int gid = blockIdx.x * blockDim.x + threadIdx.x;
    if (gid >= NB * NF) return;
    int b = gid >> 8;
    int f = gid & 255;

    const float fpj = 1.7320508075688772f;   // 1/tan(30deg)
    const float p22 = -1.0202020202020203f;  // (far+near)/(near-far)
    const float p23 = -0.20202020202020202f; // 2*far*near/(near-far)
    const float SC  = 120.11224139682566f;   // sqrt((1/SIGMA)*log2(e))
    const float ISC = 1.0f / 120.11224139682566f;

    float ex = eye[b*3+0], ey = eye[b*3+1], ez = eye[b*3+2];
    float en  = sqrtf(ex*ex + ey*ey + ez*ez);
    float izn = 1.0f / (en + 1e-8f);
    float zx = ex*izn, zy = ey*izn, zz = ez*izn;
    float cn  = sqrtf(zz*zz + zx*zx);
    float ixn = 1.0f / (cn + 1e-8f);
    float xx = zz*ixn, xy = 0.0f, xz = -zx*ixn;
    float yx = zy*xz - zz*xy;
    float yy = zz*xx - zx*xz;
    float yz = zx*xy - zy*xx;
    float tx = -(xx*ex + xy*ey + xz*ez);
    float ty = -(yx*ex + yy*ey + yz*ez);
    float tz = -(zx*ex + zy*ey + zz*ez);

    int i0 = faces[f*3+0], i1 = faces[f*3+1], i2 = faces[f*3+2];
    int idx[3] = { i0, i1, i2 };

    float ax[3], ay[3], az[3];
#pragma unroll
    for (int k = 0; k < 3; ++k) {
        const float* v = verts + (b*NV + idx[k])*3;
        float vx = v[0], vy = v[1], vz = v[2];
        float cx  = fpj*(xx*vx + xy*vy + xz*vz + tx);
        float cyv = fpj*(yx*vx + yy*vy + yz*vz + ty);
        float zv  = zx*vx + zy*vy + zz*vz + tz;
        float cz  = p22*zv + p23;
        float cw  = -zv;
        float iw  = 1.0f / (cw + 1e-8f);
        ax[k] = cx*iw; ay[k] = cyv*iw; az[k] = cz*iw;
    }

    float a0x = ax[0], a0y = ay[0];
    float a1x = ax[1], a1y = ay[1];
    float a2x = ax[2], a2y = ay[2];

    float e01x = a1x - a0x, e01y = a1y - a0y;
    float e12x = a2x - a1x, e12y = a2y - a1y;
    float e20x = a0x - a2x, e20y = a0y - a2y;

    float area  = e01x*(a2y - a0y) - e01y*(a2x - a0x);
    float denom = area + (area >= 0.0f ? 1e-12f : -1e-12f);
    float idn   = 1.0f / denom;

    float A0 = -e12y*idn, B0 = e12x*idn, C0 = (e12y*a1x - e12x*a1y)*idn;
    float A1 = -e20y*idn, B1 = e20x*idn, C1 = (e20y*a2x - e20x*a2y)*idn;
    float A2 = -e01y*idn, B2 = e01x*idn, C2 = (e01y*a0x - e01x*a0y)*idn;

    float ib01 = 1.0f / (e01x*e01x + e01y*e01y + 1e-12f);
    float ib12 = 1.0f / (e12x*e12x + e12y*e12y + 1e-12f);
    float ib20 = 1.0f / (e20x*e20x + e20y*e20y + 1e-12f);

    const float third = (1.0f/3.0f);
    float cr = (colors[(b*NV+i0)*3+0] + colors[(b*NV+i1)*3+0] + colors[(b*NV+i2)*3+0]) * third;
    float cg = (colors[(b*NV+i0)*3+1] + colors[(b*NV+i1)*3+1] + colors[(b*NV+i2)*3+1]) * third;
    float cb = (colors[(b*NV+i0)*3+2] + colors[(b*NV+i1)*3+2] + colors[(b*NV+i2)*3+2]) * third;

    // pair-interleaved write, geometry pre-scaled
    float* o = fd + (b*128 + (f >> 1))*STRIDE + (f & 1);
    o[ 0]=A0;   o[ 2]=B0;   o[ 4]=C0;
    o[ 6]=A1;   o[ 8]=B1;   o[10]=C1;
    o[12]=A2;   o[14]=B2;   o[16]=C2;
    o[18]=a0x*SC;  o[20]=a0y*SC;
    o[22]=e01x*SC; o[24]=e01y*SC; o[26]=e12x*SC; o[28]=e12y*SC; o[30]=e20x*SC; o[32]=e20y*SC;
    o[34]=e01x*ib01*ISC; o[36]=e01y*ib01*ISC;
    o[38]=e12x*ib12*ISC; o[40]=e12y*ib12*ISC;
    o[42]=e20x*ib20*ISC; o[44]=e20y*ib20*ISC;
    o[46]=az[0]; o[48]=az[1]; o[50]=az[2];
    o[52]=cr;   o[54]=cg;   o[56]=cb;
}

// block = (64,8): threadIdx.x = pixel lane, threadIdx.y = chunk of 16 face-pairs
// grid = 1024: blockIdx.x = b*256 + pixel-group
__launch_bounds__(512)
__global__ void raster(const float* __restrict__ fd, float* __restrict__ out)
{
    __shared__ float sP[8][64], sS[8][64];
    __shared__ float sR0[8][64], sR1[8][64], sR2[8][64];

    const int t   = threadIdx.x;       // 0..63
    const int cy  = threadIdx.y;       // 0..7
    const int b   = blockIdx.x >> 8;   // wave-uniform
    const int grp = blockIdx.x & 255;
    const int pixb = grp*64 + t;
    const int h = pixb >> 7;
    const int w = pixb & 127;

    const float px = (w + 0.5f) * (1.0f/64.0f) - 1.0f;
    const float py = 1.0f - (h + 0.5f) * (1.0f/64.0f);
    const float SC = 120.11224139682566f;
    const v2f px2  = { px, px };
    const v2f py2  = { py, py };
    const v2f pxs2 = { px*SC, px*SC };
    const v2f pys2 = { py*SC, py*SC };

    const float KGAM = 14.426950408889634f;  // (1/GAMMA)*log2(e)
    const v2f KGH_NEG = { -0.5f*KGAM, -0.5f*KGAM };
    const v2f KGH_POS = {  0.5f*KGAM,  0.5f*KGAM };
    const v2f ONE2 = { 1.0f, 1.0f };
    const v2f EPS2 = { 1e-8f, 1e-8f };

    int foff = (b*128 + cy*16) * STRIDE;
    foff = __builtin_amdgcn_readfirstlane(foff);
    const float* fda = (const float*)__builtin_assume_aligned(fd, 256);
    // force constant address space -> guaranteed s_load path (CK idiom)
    const CONST_AS float* fc =
        (const CONST_AS float*)(unsigned long long)(fda + foff);

    v2f prod2 = { 1.0f, 1.0f };
    v2f S2  = { 0.0f, 0.0f };
    v2f R02 = { 0.0f, 0.0f };
    v2f R12 = { 0.0f, 0.0f };
    v2f R22 = { 0.0f, 0.0f };

#pragma unroll 2
    for (int i = 0; i < 16; ++i) {
        const CONST_AS float* c = fc + i*STRIDE;
#define LD(k) (*(const CONST_AS v2f*)(c + 2*(k)))
        v2f A0 = LD(0),  B0 = LD(1),  C0 = LD(2);
        v2f A1 = LD(3),  B1 = LD(4),  C1 = LD(5);
        v2f A2 = LD(6),  B2 = LD(7),  C2 = LD(8);
        v2f a0x = LD(9), a0y = LD(10);
        v2f e01x = LD(11), e01y = LD(12);
        v2f e12x = LD(13), e12y = LD(14);
        v2f e20x = LD(15), e20y = LD(16);
        v2f g01x = LD(17), g01y = LD(18);
        v2f g12x = LD(19), g12y = LD(20);
        v2f g20x = LD(21), g20y = LD(22);
        v2f z0 = LD(23), z1 = LD(24), z2 = LD(25);
        v2f cr = LD(26), cg = LD(27), cb = LD(28);
#undef LD

        // barycentrics: 2 pk_fma each
        v2f b0 = fma2(A0, px2, fma2(B0, py2, C0));
        v2f b1 = fma2(A1, px2, fma2(B1, py2, C1));
        v2f b2 = fma2(A2, px2, fma2(B2, py2, C2));

        // pa vectors in scaled space
        v2f pa0x = pxs2 - a0x, pa0y = pys2 - a0y;
        v2f pa1x = pa0x - e01x, pa1y = pa0y - e01y;
        v2f pa2x = pa0x + e20x, pa2y = pa0y + e20y;

        // edge 01
        v2f tt = med01_2(fma2(pa0x, g01x, pa0y*g01y));
        v2f dx = fma2(-tt, e01x, pa0x);
        v2f dy = fma2(-tt, e01y, pa0y);
        v2f dd0 = fma2(dx, dx, dy*dy);
        // edge 12
        tt = med01_2(fma2(pa1x, g12x, pa1y*g12y));
        dx = fma2(-tt, e12x, pa1x);
        dy = fma2(-tt, e12y, pa1y);
        v2f dd1 = fma2(dx, dx, dy*dy);
        // edge 20
        tt = med01_2(fma2(pa2x, g20x, pa2y*g20y));
        dx = fma2(-tt, e20x, pa2x);
        dy = fma2(-tt, e20y, pa2y);
        v2f dd2 = fma2(dx, dx, dy*dy);

        // dd already scaled by (1/SIGMA)*log2e; min3 fusion per half
        float ddl = fminf(fminf(dd0.x, dd1.x), dd2.x);
        float ddh = fminf(fminf(dd0.y, dd1.y), dd2.y);
        // inside <=> max(-b) <= 0; q = copysign(dd, mx)  (v_max3 + v_bfi)
        float mxl = fmaxf(fmaxf(-b0.x, -b1.x), -b2.x);
        float mxh = fmaxf(fmaxf(-b0.y, -b1.y), -b2.y);
        float qx = copysignf(ddl, mxl);
        float qy = copysignf(ddh, mxh);

        v2f e2  = { ex2(qx), ex2(qy) };
        v2f den = e2 + ONE2;
        v2f prob = { rcpf(den.x), rcpf(den.y) };

        prod2 = fma2(-prob, prod2, prod2);   // prod *= (1-prob)

        // clamped barycentrics -> zn -> weight
        v2f bc0 = med01_2(b0), bc1 = med01_2(b1), bc2 = med01_2(b2);
        v2f s   = (bc0 + bc1) + (bc2 + EPS2);
        v2f zs  = fma2(bc0, z0, fma2(bc1, z1, bc2*z2));
        v2f irs = { rcpf(s.x), rcpf(s.y) };
        v2f zq  = fma2(zs*irs, KGH_NEG, KGH_POS);   // KGAM*(0.5 - 0.5*zp)
        float znx = __builtin_amdgcn_fmed3f(zq.x, 0.0f, KGAM);
        float zny = __builtin_amdgcn_fmed3f(zq.y, 0.0f, KGAM);
        v2f ez  = { ex2(znx), ex2(zny) };
        v2f wgt = prob * ez;

        S2  = S2 + wgt;
        R02 = fma2(wgt, cr, R02);
        R12 = fma2(wgt, cg, R12);
        R22 = fma2(wgt, cb, R22);
    }

    sP[cy][t]  = prod2.x * prod2.y;
    sS[cy][t]  = S2.x  + S2.y;
    sR0[cy][t] = R02.x + R02.y;
    sR1[cy][t] = R12.x + R12.y;
    sR2[cy][t] = R22.x + R22.y;
    __syncthreads();

    if (cy == 0) {
        float P  = 1.0f, St = 0.0f, r0 = 0.0f, r1 = 0.0f, r2 = 0.0f;
#pragma unroll
        for (int c2 = 0; c2 < 8; ++c2) {
            P  *= sP[c2][t];
            St += sS[c2][t];
            r0 += sR0[c2][t];
            r1 += sR1[c2][t];
            r2 += sR2[c2][t];
        }
        float iden = rcpf(St + 1.0f);   // background weight = exp2(0) = 1

        out[b*16384 + pixb] = 1.0f - P;
        float* rgb = out + 65536;
        rgb[(b*3 + 0)*16384 + pixb] = r0 * iden;
        rgb[(b*3 + 1)*16384 + pixb] = r1 * iden;
        rgb[(b*3 + 2)*16384 + pixb] = r2 * iden;
    }
}

extern "C" void kernel_launch(void* const* d_in, const int* in_sizes, int n_in,
                              void* d_out, int out_size, void* d_ws, size_t ws_size,
                              hipStream_t stream)
{
    const float* verts  = (const float*)d_in[0];
    const int*   faces  = (const int*)d_in[1];
    const float* colors = (const float*)d_in[2];
    const float* eye    = (const float*)d_in[3];
    float* out = (float*)d_out;
    float* fd  = (float*)d_ws;  // 4*128 pairs * 64 floats = 128 KB

    hipLaunchKernelGGL(prep_faces, dim3(4), dim3(256), 0, stream,
                       verts, faces, colors, eye, fd);
    hipLaunchKernelGGL(raster, dim3(1024), dim3(64, 8), 0, stream, fd, out);
}

// Round 5
// 34.869 us; speedup vs baseline: 1.5010x; 1.0194x over previous
//
#include <hip/hip_runtime.h>

#define NB 4
#define NV 256
#define NF 256
#define IMG 128
#define STRIDE 64   // floats per face-PAIR block (29 slots x 2 = 58, padded to 64 -> 256B)

typedef float v2f __attribute__((ext_vector_type(2)));

__device__ __forceinline__ float rcpf(float x) { return __builtin_amdgcn_rcpf(x); }
__device__ __forceinline__ float ex2(float x)  { return __builtin_amdgcn_exp2f(x); }
__device__ __forceinline__ float med01(float x) { return __builtin_amdgcn_fmed3f(x, 0.0f, 1.0f); }
__device__ __forceinline__ v2f med01_2(v2f v) { return (v2f){ med01(v.x), med01(v.y) }; }
__device__ __forceinline__ v2f fma2(v2f a, v2f b, v2f c) { return __builtin_elementwise_fma(a, b, c); }

// slot layout (pair-interleaved: value k of face f at [2k + (f&1)]), geometry pre-scaled by s=sqrt(KSIG):
//  0 A0  1 B0  2 C0  3 A1  4 B1  5 C1  6 A2  7 B2  8 C2      (barycentric affine, UNscaled)
//  9 a0x*s 10 a0y*s
// 11 e01x*s 12 e01y*s 13 e12x*s 14 e12y*s 15 e20x*s 16 e20y*s
// 17 g01x/s 18 g01y/s 19 g12x/s 20 g12y/s 21 g20x/s 22 g20y/s  (g = e/(|e|^2+1e-12))
// 23 z0 24 z1 25 z2  26 cr 27 cg 28 cb

__global__ void prep_faces(const float* __restrict__ verts,
                           const int* __restrict__ faces,
                           const float* __restrict__ colors,
                           const float* __restrict__ eye,
                           float* __restrict__ fd)
{
    int gid = blockIdx.x * blockDim.x + threadIdx.x;
    if (gid >= NB * NF) return;
    int b = gid >> 8;
    int f = gid & 255;

    const float fpj = 1.7320508075688772f;   // 1/tan(30deg)
    const float p22 = -1.0202020202020203f;  // (far+near)/(near-far)
    const float p23 = -0.20202020202020202f; // 2*far*near/(near-far)
    const float SC  = 120.11224139682566f;   // sqrt((1/SIGMA)*log2(e))
    const float ISC = 1.0f / 120.11224139682566f;

    float ex = eye[b*3+0], ey = eye[b*3+1], ez = eye[b*3+2];
    float en  = sqrtf(ex*ex + ey*ey + ez*ez);
    float izn = 1.0f / (en + 1e-8f);
    float zx = ex*izn, zy = ey*izn, zz = ez*izn;
    float cn  = sqrtf(zz*zz + zx*zx);
    float ixn = 1.0f / (cn + 1e-8f);
    float xx = zz*ixn, xy = 0.0f, xz = -zx*ixn;
    float yx = zy*xz - zz*xy;
    float yy = zz*xx - zx*xz;
    float yz = zx*xy - zy*xx;
    float tx = -(xx*ex + xy*ey + xz*ez);
    float ty = -(yx*ex + yy*ey + yz*ez);
    float tz = -(zx*ex + zy*ey + zz*ez);

    int i0 = faces[f*3+0], i1 = faces[f*3+1], i2 = faces[f*3+2];
    int idx[3] = { i0, i1, i2 };

    float ax[3], ay[3], az[3];
#pragma unroll
    for (int k = 0; k < 3; ++k) {
        const float* v = verts + (b*NV + idx[k])*3;
        float vx = v[0], vy = v[1], vz = v[2];
        float cx  = fpj*(xx*vx + xy*vy + xz*vz + tx);
        float cyv = fpj*(yx*vx + yy*vy + yz*vz + ty);
        float zv  = zx*vx + zy*vy + zz*vz + tz;
        float cz  = p22*zv + p23;
        float cw  = -zv;
        float iw  = 1.0f / (cw + 1e-8f);
        ax[k] = cx*iw; ay[k] = cyv*iw; az[k] = cz*iw;
    }

    float a0x = ax[0], a0y = ay[0];
    float a1x = ax[1], a1y = ay[1];
    float a2x = ax[2], a2y = ay[2];

    float e01x = a1x - a0x, e01y = a1y - a0y;
    float e12x = a2x - a1x, e12y = a2y - a1y;
    float e20x = a0x - a2x, e20y = a0y - a2y;

    float area  = e01x*(a2y - a0y) - e01y*(a2x - a0x);
    float denom = area + (area >= 0.0f ? 1e-12f : -1e-12f);
    float idn   = 1.0f / denom;

    float A0 = -e12y*idn, B0 = e12x*idn, C0 = (e12y*a1x - e12x*a1y)*idn;
    float A1 = -e20y*idn, B1 = e20x*idn, C1 = (e20y*a2x - e20x*a2y)*idn;
    float A2 = -e01y*idn, B2 = e01x*idn, C2 = (e01y*a0x - e01x*a0y)*idn;

    float ib01 = 1.0f / (e01x*e01x + e01y*e01y + 1e-12f);
    float ib12 = 1.0f / (e12x*e12x + e12y*e12y + 1e-12f);
    float ib20 = 1.0f / (e20x*e20x + e20y*e20y + 1e-12f);

    const float third = (1.0f/3.0f);
    float cr = (colors[(b*NV+i0)*3+0] + colors[(b*NV+i1)*3+0] + colors[(b*NV+i2)*3+0]) * third;
    float cg = (colors[(b*NV+i0)*3+1] + colors[(b*NV+i1)*3+1] + colors[(b*NV+i2)*3+1]) * third;
    float cb = (colors[(b*NV+i0)*3+2] + colors[(b*NV+i1)*3+2] + colors[(b*NV+i2)*3+2]) * third;

    // pair-interleaved write, geometry pre-scaled
    float* o = fd + (b*128 + (f >> 1))*STRIDE + (f & 1);
    o[ 0]=A0;   o[ 2]=B0;   o[ 4]=C0;
    o[ 6]=A1;   o[ 8]=B1;   o[10]=C1;
    o[12]=A2;   o[14]=B2;   o[16]=C2;
    o[18]=a0x*SC;  o[20]=a0y*SC;
    o[22]=e01x*SC; o[24]=e01y*SC; o[26]=e12x*SC; o[28]=e12y*SC; o[30]=e20x*SC; o[32]=e20y*SC;
    o[34]=e01x*ib01*ISC; o[36]=e01y*ib01*ISC;
    o[38]=e12x*ib12*ISC; o[40]=e12y*ib12*ISC;
    o[42]=e20x*ib20*ISC; o[44]=e20y*ib20*ISC;
    o[46]=az[0]; o[48]=az[1]; o[50]=az[2];
    o[52]=cr;   o[54]=cg;   o[56]=cb;
    o[58]=0.0f; o[60]=0.0f; o[62]=0.0f;   // pad (keeps staging reads defined)
}

// block = (64,8): threadIdx.x = pixel lane, threadIdx.y = chunk of 16 face-pairs
// grid = 1024: blockIdx.x = b*256 + pixel-group
__launch_bounds__(512)
__global__ void raster(const float* __restrict__ fd, float* __restrict__ out)
{
    // 32 KB: face table during the loop, reduction arrays after (aliased)
    __shared__ float sFD[8192];

    const int t   = threadIdx.x;       // 0..63
    const int cy  = threadIdx.y;       // 0..7
    const int b   = blockIdx.x >> 8;
    const int grp = blockIdx.x & 255;
    const int pixb = grp*64 + t;
    const int h = pixb >> 7;
    const int w = pixb & 127;

    // stage the whole per-batch face table: 8192 floats = 2048 float4, 4/thread
    {
        const float4* src = (const float4*)(fd + (b << 13));
        float4* dst = (float4*)sFD;
        int tid = (cy << 6) + t;       // 0..511
#pragma unroll
        for (int k = 0; k < 4; ++k) dst[tid + (k << 9)] = src[tid + (k << 9)];
    }
    __syncthreads();

    const float px = (w + 0.5f) * (1.0f/64.0f) - 1.0f;
    const float py = 1.0f - (h + 0.5f) * (1.0f/64.0f);
    const float SC = 120.11224139682566f;
    const v2f px2  = { px, px };
    const v2f py2  = { py, py };
    const v2f pxs2 = { px*SC, px*SC };
    const v2f pys2 = { py*SC, py*SC };

    const float KGAM = 14.426950408889634f;  // (1/GAMMA)*log2(e)
    const v2f KGH_NEG = { -0.5f*KGAM, -0.5f*KGAM };
    const v2f KGH_POS = {  0.5f*KGAM,  0.5f*KGAM };
    const v2f ONE2 = { 1.0f, 1.0f };
    const v2f EPS2 = { 1e-8f, 1e-8f };

    const float* fc = sFD + cy*(16*STRIDE);

    v2f prod2 = { 1.0f, 1.0f };
    v2f S2  = { 0.0f, 0.0f };
    v2f R02 = { 0.0f, 0.0f };
    v2f R12 = { 0.0f, 0.0f };
    v2f R22 = { 0.0f, 0.0f };

#pragma unroll 2
    for (int i = 0; i < 16; ++i) {
        const float* c = fc + i*STRIDE;
#define LD(k) (*(const v2f*)(c + 2*(k)))
        v2f A0 = LD(0),  B0 = LD(1),  C0 = LD(2);
        v2f A1 = LD(3),  B1 = LD(4),  C1 = LD(5);
        v2f A2 = LD(6),  B2 = LD(7),  C2 = LD(8);
        v2f a0x = LD(9), a0y = LD(10);
        v2f e01x = LD(11), e01y = LD(12);
        v2f e12x = LD(13), e12y = LD(14);
        v2f e20x = LD(15), e20y = LD(16);
        v2f g01x = LD(17), g01y = LD(18);
        v2f g12x = LD(19), g12y = LD(20);
        v2f g20x = LD(21), g20y = LD(22);
        v2f z0 = LD(23), z1 = LD(24), z2 = LD(25);
        v2f cr = LD(26), cg = LD(27), cb = LD(28);
#undef LD

        // barycentrics: 2 pk_fma each
        v2f b0 = fma2(A0, px2, fma2(B0, py2, C0));
        v2f b1 = fma2(A1, px2, fma2(B1, py2, C1));
        v2f b2 = fma2(A2, px2, fma2(B2, py2, C2));

        // pa vectors in scaled space
        v2f pa0x = pxs2 - a0x, pa0y = pys2 - a0y;
        v2f pa1x = pa0x - e01x, pa1y = pa0y - e01y;
        v2f pa2x = pa0x + e20x, pa2y = pa0y + e20y;

        // edge 01
        v2f tt = med01_2(fma2(pa0x, g01x, pa0y*g01y));
        v2f dx = fma2(-tt, e01x, pa0x);
        v2f dy = fma2(-tt, e01y, pa0y);
        v2f dd0 = fma2(dx, dx, dy*dy);
        // edge 12
        tt = med01_2(fma2(pa1x, g12x, pa1y*g12y));
        dx = fma2(-tt, e12x, pa1x);
        dy = fma2(-tt, e12y, pa1y);
        v2f dd1 = fma2(dx, dx, dy*dy);
        // edge 20
        tt = med01_2(fma2(pa2x, g20x, pa2y*g20y));
        dx = fma2(-tt, e20x, pa2x);
        dy = fma2(-tt, e20y, pa2y);
        v2f dd2 = fma2(dx, dx, dy*dy);

        // dd already scaled by (1/SIGMA)*log2e
        float ddl = fminf(fminf(dd0.x, dd1.x), dd2.x);
        float ddh = fminf(fminf(dd0.y, dd1.y), dd2.y);
        // inside <=> max(-b) <= 0; q = copysign(dd, mx)
        float mxl = fmaxf(fmaxf(-b0.x, -b1.x), -b2.x);
        float mxh = fmaxf(fmaxf(-b0.y, -b1.y), -b2.y);
        float qx = copysignf(ddl, mxl);
        float qy = copysignf(ddh, mxh);

        v2f e2  = { ex2(qx), ex2(qy) };
        v2f den = e2 + ONE2;
        v2f prob = { rcpf(den.x), rcpf(den.y) };

        prod2 = fma2(-prob, prod2, prod2);   // prod *= (1-prob)

        // clamped barycentrics -> zn -> weight
        v2f bc0 = med01_2(b0), bc1 = med01_2(b1), bc2 = med01_2(b2);
        v2f s   = (bc0 + bc1) + (bc2 + EPS2);
        v2f zs  = fma2(bc0, z0, fma2(bc1, z1, bc2*z2));
        v2f irs = { rcpf(s.x), rcpf(s.y) };
        v2f zq  = fma2(zs*irs, KGH_NEG, KGH_POS);   // KGAM*(0.5 - 0.5*zp)
        float znx = __builtin_amdgcn_fmed3f(zq.x, 0.0f, KGAM);
        float zny = __builtin_amdgcn_fmed3f(zq.y, 0.0f, KGAM);
        v2f ez  = { ex2(znx), ex2(zny) };
        v2f wgt = prob * ez;

        S2  = S2 + wgt;
        R02 = fma2(wgt, cr, R02);
        R12 = fma2(wgt, cg, R12);
        R22 = fma2(wgt, cb, R22);
    }

    // table reads complete -> alias reductions into the same LDS
    __syncthreads();
    float* red = sFD;   // 5 arrays of [8][64]
    red[(0*8 + cy)*64 + t] = prod2.x * prod2.y;
    red[(1*8 + cy)*64 + t] = S2.x  + S2.y;
    red[(2*8 + cy)*64 + t] = R02.x + R02.y;
    red[(3*8 + cy)*64 + t] = R12.x + R12.y;
    red[(4*8 + cy)*64 + t] = R22.x + R22.y;
    __syncthreads();

    if (cy == 0) {
        float P  = 1.0f, St = 0.0f, r0 = 0.0f, r1 = 0.0f, r2 = 0.0f;
#pragma unroll
        for (int c2 = 0; c2 < 8; ++c2) {
            P  *= red[(0*8 + c2)*64 + t];
            St += red[(1*8 + c2)*64 + t];
            r0 += red[(2*8 + c2)*64 + t];
            r1 += red[(3*8 + c2)*64 + t];
            r2 += red[(4*8 + c2)*64 + t];
        }
        float iden = rcpf(St + 1.0f);   // background weight = exp2(0) = 1

        out[b*16384 + pixb] = 1.0f - P;
        float* rgb = out + 65536;
        rgb[(b*3 + 0)*16384 + pixb] = r0 * iden;
        rgb[(b*3 + 1)*16384 + pixb] = r1 * iden;
        rgb[(b*3 + 2)*16384 + pixb] = r2 * iden;
    }
}

extern "C" void kernel_launch(void* const* d_in, const int* in_sizes, int n_in,
                              void* d_out, int out_size, void* d_ws, size_t ws_size,
                              hipStream_t stream)
{
    const float* verts  = (const float*)d_in[0];
    const int*   faces  = (const int*)d_in[1];
    const float* colors = (const float*)d_in[2];
    const float* eye    = (const float*)d_in[3];
    float* out = (float*)d_out;
    float* fd  = (float*)d_ws;  // 4*128 pairs * 64 floats = 128 KB

    hipLaunchKernelGGL(prep_faces, dim3(4), dim3(256), 0, stream,
                       verts, faces, colors, eye, fd);
    hipLaunchKernelGGL(raster, dim3(1024), dim3(64, 8), 0, stream, fd, out);
}

// Round 6
// 33.274 us; speedup vs baseline: 1.5730x; 1.0480x over previous
//
#include <hip/hip_runtime.h>

#define NB 4
#define NV 256
#define NF 256
#define IMG 128
#define STR 32   // floats per face-PAIR record (16 values x 2, 128B)

typedef float v2f __attribute__((ext_vector_type(2)));

__device__ __forceinline__ float rcpf(float x) { return __builtin_amdgcn_rcpf(x); }
__device__ __forceinline__ float ex2(float x)  { return __builtin_amdgcn_exp2f(x); }
__device__ __forceinline__ float med01(float x) { return __builtin_amdgcn_fmed3f(x, 0.0f, 1.0f); }
__device__ __forceinline__ v2f med01_2(v2f v) { return (v2f){ med01(v.x), med01(v.y) }; }
__device__ __forceinline__ v2f fma2(v2f a, v2f b, v2f c) { return __builtin_elementwise_fma(a, b, c); }

// pair-interleaved record, value k of face f at [2k + (f&1)], geometry scaled by SC=sqrt(KSIG):
//  0 a0x*SC  1 a0y*SC  2 e01x*SC  3 e01y*SC  4 e12x*SC  5 e12y*SC
//  6 ib01/KSIG  7 ib12/KSIG  8 ib20/KSIG      (ib = 1/(|e|^2+1e-12), unscaled space)
//  9 idn/KSIG   10 z0 11 z1 12 z2  13 cr 14 cg 15 cb
// derived in-kernel: e20 = -(e01+e12), g = e*ib'

__global__ void prep_faces(const float* __restrict__ verts,
                           const int* __restrict__ faces,
                           const float* __restrict__ colors,
                           const float* __restrict__ eye,
                           float* __restrict__ fd)
{
    int gid = blockIdx.x * blockDim.x + threadIdx.x;
    if (gid >= NB * NF) return;
    int b = gid >> 8;
    int f = gid & 255;

    const float fpj = 1.7320508075688772f;   // 1/tan(30deg)
    const float p22 = -1.0202020202020203f;  // (far+near)/(near-far)
    const float p23 = -0.20202020202020202f; // 2*far*near/(near-far)
    const float SC   = 120.11224139682566f;  // sqrt((1/SIGMA)*log2(e))
    const float ISC2 = 6.931471805599453e-05f; // 1/KSIG = SIGMA*ln(2)

    float ex = eye[b*3+0], ey = eye[b*3+1], ez = eye[b*3+2];
    float en  = sqrtf(ex*ex + ey*ey + ez*ez);
    float izn = 1.0f / (en + 1e-8f);
    float zx = ex*izn, zy = ey*izn, zz = ez*izn;
    float cn  = sqrtf(zz*zz + zx*zx);
    float ixn = 1.0f / (cn + 1e-8f);
    float xx = zz*ixn, xy = 0.0f, xz = -zx*ixn;
    float yx = zy*xz - zz*xy;
    float yy = zz*xx - zx*xz;
    float yz = zx*xy - zy*xx;
    float tx = -(xx*ex + xy*ey + xz*ez);
    float ty = -(yx*ex + yy*ey + yz*ez);
    float tz = -(zx*ex + zy*ey + zz*ez);

    int i0 = faces[f*3+0], i1 = faces[f*3+1], i2 = faces[f*3+2];
    int idx[3] = { i0, i1, i2 };

    float ax[3], ay[3], az[3];
#pragma unroll
    for (int k = 0; k < 3; ++k) {
        const float* v = verts + (b*NV + idx[k])*3;
        float vx = v[0], vy = v[1], vz = v[2];
        float cx  = fpj*(xx*vx + xy*vy + xz*vz + tx);
        float cyv = fpj*(yx*vx + yy*vy + yz*vz + ty);
        float zv  = zx*vx + zy*vy + zz*vz + tz;
        float cz  = p22*zv + p23;
        float cw  = -zv;
        float iw  = 1.0f / (cw + 1e-8f);
        ax[k] = cx*iw; ay[k] = cyv*iw; az[k] = cz*iw;
    }

    float a0x = ax[0], a0y = ay[0];
    float a1x = ax[1], a1y = ay[1];
    float a2x = ax[2], a2y = ay[2];

    float e01x = a1x - a0x, e01y = a1y - a0y;
    float e12x = a2x - a1x, e12y = a2y - a1y;
    float e20x = a0x - a2x, e20y = a0y - a2y;

    float area  = e01x*(a2y - a0y) - e01y*(a2x - a0x);
    float denom = area + (area >= 0.0f ? 1e-12f : -1e-12f);
    float idn   = 1.0f / denom;

    float ib01 = 1.0f / (e01x*e01x + e01y*e01y + 1e-12f);
    float ib12 = 1.0f / (e12x*e12x + e12y*e12y + 1e-12f);
    float ib20 = 1.0f / (e20x*e20x + e20y*e20y + 1e-12f);

    const float third = (1.0f/3.0f);
    float cr = (colors[(b*NV+i0)*3+0] + colors[(b*NV+i1)*3+0] + colors[(b*NV+i2)*3+0]) * third;
    float cg = (colors[(b*NV+i0)*3+1] + colors[(b*NV+i1)*3+1] + colors[(b*NV+i2)*3+1]) * third;
    float cb = (colors[(b*NV+i0)*3+2] + colors[(b*NV+i1)*3+2] + colors[(b*NV+i2)*3+2]) * third;

    float* o = fd + (b*128 + (f >> 1))*STR + (f & 1);
    o[ 0]=a0x*SC;   o[ 2]=a0y*SC;
    o[ 4]=e01x*SC;  o[ 6]=e01y*SC;
    o[ 8]=e12x*SC;  o[10]=e12y*SC;
    o[12]=ib01*ISC2; o[14]=ib12*ISC2; o[16]=ib20*ISC2;
    o[18]=idn*ISC2;
    o[20]=az[0]; o[22]=az[1]; o[24]=az[2];
    o[26]=cr;   o[28]=cg;   o[30]=cb;
}

// block = (64,8): threadIdx.x = pixel lane, threadIdx.y = chunk of 16 face-pairs
// each thread handles TWO pixels (pix0 = grp*128+t, pix1 = pix0+64)
// grid = 512: blockIdx.x = b*128 + pixel-group(128px)
__launch_bounds__(512, 4)
__global__ void raster(const float* __restrict__ fd, float* __restrict__ out)
{
    // 16KB face table during the loop; 20KB reduction arrays after (aliased)
    __shared__ float sFD[5120];

    const int t   = threadIdx.x;       // 0..63
    const int cy  = threadIdx.y;       // 0..7
    const int b   = blockIdx.x >> 7;
    const int grp = blockIdx.x & 127;
    const int pix0 = grp*128 + t;
    const int pix1 = pix0 + 64;

    // stage the per-batch face table: 4096 floats = 1024 float4, 2/thread
    {
        const float4* src = (const float4*)(fd + (b << 12));
        float4* dst = (float4*)sFD;
        int tid = (cy << 6) + t;       // 0..511
        dst[tid]       = src[tid];
        dst[tid + 512] = src[tid + 512];
    }
    __syncthreads();

    const float SC = 120.11224139682566f;
    const float KGAM = 14.426950408889634f;  // (1/GAMMA)*log2(e)
    const v2f KGH_NEG = { -0.5f*KGAM, -0.5f*KGAM };
    const v2f KGH_POS = {  0.5f*KGAM,  0.5f*KGAM };
    const v2f ONE2 = { 1.0f, 1.0f };
    const v2f EPS2 = { 1e-8f, 1e-8f };

    // pixel coords (scaled space) for both pixels
    const int h0 = pix0 >> 7, w0 = pix0 & 127;
    const int h1 = pix1 >> 7, w1 = pix1 & 127;
    const float pxa = ((w0 + 0.5f) * (1.0f/64.0f) - 1.0f) * SC;
    const float pya = (1.0f - (h0 + 0.5f) * (1.0f/64.0f)) * SC;
    const float pxb = ((w1 + 0.5f) * (1.0f/64.0f) - 1.0f) * SC;
    const float pyb = (1.0f - (h1 + 0.5f) * (1.0f/64.0f)) * SC;
    const v2f PXA = { pxa, pxa }, PYA = { pya, pya };
    const v2f PXB = { pxb, pxb }, PYB = { pyb, pyb };

    const float* fc = sFD + cy*(16*STR);

    v2f A_prod = ONE2, A_S = {0,0}, A_R0 = {0,0}, A_R1 = {0,0}, A_R2 = {0,0};
    v2f B_prod = ONE2, B_S = {0,0}, B_R0 = {0,0}, B_R1 = {0,0}, B_R2 = {0,0};

#define PIXEL(PXS, PYS, AP, AS, AR0, AR1, AR2) do {                      \
    v2f pa0x = PXS - a0x, pa0y = PYS - a0y;                              \
    v2f pa1x = pa0x - e01x, pa1y = pa0y - e01y;                          \
    v2f pa2x = pa0x + e20x, pa2y = pa0y + e20y;                          \
    v2f b0 = fma2(-e12y, pa1x, e12x*pa1y) * idn;                         \
    v2f b1 = fma2(-e20y, pa2x, e20x*pa2y) * idn;                         \
    v2f b2 = fma2(-e01y, pa0x, e01x*pa0y) * idn;                         \
    v2f tt = med01_2(fma2(pa0x, g01x, pa0y*g01y));                       \
    v2f dx = fma2(-tt, e01x, pa0x);                                      \
    v2f dy = fma2(-tt, e01y, pa0y);                                      \
    v2f dd0 = fma2(dx, dx, dy*dy);                                       \
    tt = med01_2(fma2(pa1x, g12x, pa1y*g12y));                           \
    dx = fma2(-tt, e12x, pa1x);                                          \
    dy = fma2(-tt, e12y, pa1y);                                          \
    v2f dd1 = fma2(dx, dx, dy*dy);                                       \
    tt = med01_2(fma2(pa2x, g20x, pa2y*g20y));                           \
    dx = fma2(-tt, e20x, pa2x);                                          \
    dy = fma2(-tt, e20y, pa2y);                                          \
    v2f dd2 = fma2(dx, dx, dy*dy);                                       \
    float ddl = fminf(fminf(dd0.x, dd1.x), dd2.x);                       \
    float ddh = fminf(fminf(dd0.y, dd1.y), dd2.y);                       \
    float mxl = fmaxf(fmaxf(-b0.x, -b1.x), -b2.x);                       \
    float mxh = fmaxf(fmaxf(-b0.y, -b1.y), -b2.y);                       \
    float qx = copysignf(ddl, mxl);                                      \
    float qy = copysignf(ddh, mxh);                                      \
    v2f e2 = { ex2(qx), ex2(qy) };                                       \
    v2f den = e2 + ONE2;                                                 \
    v2f prob = { rcpf(den.x), rcpf(den.y) };                             \
    AP = fma2(-prob, AP, AP);                                            \
    v2f bc0 = med01_2(b0), bc1 = med01_2(b1), bc2 = med01_2(b2);         \
    v2f s = (bc0 + bc1) + (bc2 + EPS2);                                  \
    v2f zs = fma2(bc0, z0, fma2(bc1, z1, bc2*z2));                       \
    v2f irs = { rcpf(s.x), rcpf(s.y) };                                  \
    v2f zq = fma2(zs*irs, KGH_NEG, KGH_POS);                             \
    float znx = __builtin_amdgcn_fmed3f(zq.x, 0.0f, KGAM);               \
    float zny = __builtin_amdgcn_fmed3f(zq.y, 0.0f, KGAM);               \
    v2f ez = { ex2(znx), ex2(zny) };                                     \
    v2f wgt = prob * ez;                                                 \
    AS = AS + wgt;                                                       \
    AR0 = fma2(wgt, cr, AR0);                                            \
    AR1 = fma2(wgt, cg, AR1);                                            \
    AR2 = fma2(wgt, cb, AR2);                                            \
} while (0)

    for (int i = 0; i < 16; ++i) {
        const float* c = fc + i*STR;
#define LD(k) (*(const v2f*)(c + 2*(k)))
        v2f a0x = LD(0), a0y = LD(1);
        v2f e01x = LD(2), e01y = LD(3);
        v2f e12x = LD(4), e12y = LD(5);
        v2f ib01 = LD(6), ib12 = LD(7), ib20 = LD(8);
        v2f idn = LD(9);
        v2f z0 = LD(10), z1 = LD(11), z2 = LD(12);
        v2f cr = LD(13), cg = LD(14), cb = LD(15);
#undef LD
        // shared per-pair derivation
        v2f e20x = -(e01x + e12x), e20y = -(e01y + e12y);
        v2f g01x = e01x*ib01, g01y = e01y*ib01;
        v2f g12x = e12x*ib12, g12y = e12y*ib12;
        v2f g20x = e20x*ib20, g20y = e20y*ib20;

        PIXEL(PXA, PYA, A_prod, A_S, A_R0, A_R1, A_R2);
        PIXEL(PXB, PYB, B_prod, B_S, B_R0, B_R1, B_R2);
    }
#undef PIXEL

    // table reads complete -> alias reductions into the same LDS
    __syncthreads();
    float* red = sFD;   // 10 arrays of [8][64]: [(acc*2 + j)*8 + cy][t]
    red[((0*2+0)*8 + cy)*64 + t] = A_prod.x * A_prod.y;
    red[((0*2+1)*8 + cy)*64 + t] = B_prod.x * B_prod.y;
    red[((1*2+0)*8 + cy)*64 + t] = A_S.x  + A_S.y;
    red[((1*2+1)*8 + cy)*64 + t] = B_S.x  + B_S.y;
    red[((2*2+0)*8 + cy)*64 + t] = A_R0.x + A_R0.y;
    red[((2*2+1)*8 + cy)*64 + t] = B_R0.x + B_R0.y;
    red[((3*2+0)*8 + cy)*64 + t] = A_R1.x + A_R1.y;
    red[((3*2+1)*8 + cy)*64 + t] = B_R1.x + B_R1.y;
    red[((4*2+0)*8 + cy)*64 + t] = A_R2.x + A_R2.y;
    red[((4*2+1)*8 + cy)*64 + t] = B_R2.x + B_R2.y;
    __syncthreads();

    if (cy == 0) {
#pragma unroll
        for (int j = 0; j < 2; ++j) {
            float P  = 1.0f, St = 0.0f, r0 = 0.0f, r1 = 0.0f, r2 = 0.0f;
#pragma unroll
            for (int c2 = 0; c2 < 8; ++c2) {
                P  *= red[((0*2+j)*8 + c2)*64 + t];
                St += red[((1*2+j)*8 + c2)*64 + t];
                r0 += red[((2*2+j)*8 + c2)*64 + t];
                r1 += red[((3*2+j)*8 + c2)*64 + t];
                r2 += red[((4*2+j)*8 + c2)*64 + t];
            }
            float iden = rcpf(St + 1.0f);   // background weight = exp2(0) = 1
            int pix = (j == 0) ? pix0 : pix1;

            out[b*16384 + pix] = 1.0f - P;
            float* rgb = out + 65536;
            rgb[(b*3 + 0)*16384 + pix] = r0 * iden;
            rgb[(b*3 + 1)*16384 + pix] = r1 * iden;
            rgb[(b*3 + 2)*16384 + pix] = r2 * iden;
        }
    }
}

extern "C" void kernel_launch(void* const* d_in, const int* in_sizes, int n_in,
                              void* d_out, int out_size, void* d_ws, size_t ws_size,
                              hipStream_t stream)
{
    const float* verts  = (const float*)d_in[0];
    const int*   faces  = (const int*)d_in[1];
    const float* colors = (const float*)d_in[2];
    const float* eye    = (const float*)d_in[3];
    float* out = (float*)d_out;
    float* fd  = (float*)d_ws;  // 4*128 pairs * 32 floats = 64 KB

    hipLaunchKernelGGL(prep_faces, dim3(4), dim3(256), 0, stream,
                       verts, faces, colors, eye, fd);
    hipLaunchKernelGGL(raster, dim3(512), dim3(64, 8), 0, stream, fd, out);
}

// Round 7
// 31.245 us; speedup vs baseline: 1.6751x; 1.0649x over previous
//
#include <hip/hip_runtime.h>

#define NB 4
#define NV 256
#define NF 256
#define IMG 128
#define STR 32   // floats per face-PAIR record (16 values x 2, 128B)

typedef float v2f __attribute__((ext_vector_type(2)));

__device__ __forceinline__ float rcpf(float x) { return __builtin_amdgcn_rcpf(x); }
__device__ __forceinline__ float ex2(float x)  { return __builtin_amdgcn_exp2f(x); }
__device__ __forceinline__ float med01(float x) { return __builtin_amdgcn_fmed3f(x, 0.0f, 1.0f); }
__device__ __forceinline__ v2f med01_2(v2f v) { return (v2f){ med01(v.x), med01(v.y) }; }
__device__ __forceinline__ v2f fma2(v2f a, v2f b, v2f c) { return __builtin_elementwise_fma(a, b, c); }

// pair-interleaved record, value k of face f at [2k + (f&1)], geometry scaled by SC=sqrt(KSIG):
//  0 a0x*SC  1 a0y*SC  2 e01x*SC  3 e01y*SC  4 e12x*SC  5 e12y*SC
//  6 ib01/KSIG  7 ib12/KSIG  8 ib20/KSIG   9 idn/KSIG
// 10 z0 11 z1 12 z2  13 cr 14 cg 15 cb

__global__ void prep_faces(const float* __restrict__ verts,
                           const int* __restrict__ faces,
                           const float* __restrict__ colors,
                           const float* __restrict__ eye,
                           float* __restrict__ fd)
{
    int gid = blockIdx.x * blockDim.x + threadIdx.x;
    if (gid >= NB * NF) return;
    int b = gid >> 8;
    int f = gid & 255;

    const float fpj = 1.7320508075688772f;   // 1/tan(30deg)
    const float p22 = -1.0202020202020203f;  // (far+near)/(near-far)
    const float p23 = -0.20202020202020202f; // 2*far*near/(near-far)
    const float SC   = 120.11224139682566f;  // sqrt((1/SIGMA)*log2(e))
    const float ISC2 = 6.931471805599453e-05f; // 1/KSIG

    float ex = eye[b*3+0], ey = eye[b*3+1], ez = eye[b*3+2];
    float en  = sqrtf(ex*ex + ey*ey + ez*ez);
    float izn = 1.0f / (en + 1e-8f);
    float zx = ex*izn, zy = ey*izn, zz = ez*izn;
    float cn  = sqrtf(zz*zz + zx*zx);
    float ixn = 1.0f / (cn + 1e-8f);
    float xx = zz*ixn, xy = 0.0f, xz = -zx*ixn;
    float yx = zy*xz - zz*xy;
    float yy = zz*xx - zx*xz;
    float yz = zx*xy - zy*xx;
    float tx = -(xx*ex + xy*ey + xz*ez);
    float ty = -(yx*ex + yy*ey + yz*ez);
    float tz = -(zx*ex + zy*ey + zz*ez);

    int i0 = faces[f*3+0], i1 = faces[f*3+1], i2 = faces[f*3+2];
    int idx[3] = { i0, i1, i2 };

    float ax[3], ay[3], az[3];
#pragma unroll
    for (int k = 0; k < 3; ++k) {
        const float* v = verts + (b*NV + idx[k])*3;
        float vx = v[0], vy = v[1], vz = v[2];
        float cx  = fpj*(xx*vx + xy*vy + xz*vz + tx);
        float cyv = fpj*(yx*vx + yy*vy + yz*vz + ty);
        float zv  = zx*vx + zy*vy + zz*vz + tz;
        float cz  = p22*zv + p23;
        float cw  = -zv;
        float iw  = 1.0f / (cw + 1e-8f);
        ax[k] = cx*iw; ay[k] = cyv*iw; az[k] = cz*iw;
    }

    float a0x = ax[0], a0y = ay[0];
    float a1x = ax[1], a1y = ay[1];
    float a2x = ax[2], a2y = ay[2];

    float e01x = a1x - a0x, e01y = a1y - a0y;
    float e12x = a2x - a1x, e12y = a2y - a1y;
    float e20x = a0x - a2x, e20y = a0y - a2y;

    float area  = e01x*(a2y - a0y) - e01y*(a2x - a0x);
    float denom = area + (area >= 0.0f ? 1e-12f : -1e-12f);
    float idn   = 1.0f / denom;

    float ib01 = 1.0f / (e01x*e01x + e01y*e01y + 1e-12f);
    float ib12 = 1.0f / (e12x*e12x + e12y*e12y + 1e-12f);
    float ib20 = 1.0f / (e20x*e20x + e20y*e20y + 1e-12f);

    const float third = (1.0f/3.0f);
    float cr = (colors[(b*NV+i0)*3+0] + colors[(b*NV+i1)*3+0] + colors[(b*NV+i2)*3+0]) * third;
    float cg = (colors[(b*NV+i0)*3+1] + colors[(b*NV+i1)*3+1] + colors[(b*NV+i2)*3+1]) * third;
    float cb = (colors[(b*NV+i0)*3+2] + colors[(b*NV+i1)*3+2] + colors[(b*NV+i2)*3+2]) * third;

    float* o = fd + (b*128 + (f >> 1))*STR + (f & 1);
    o[ 0]=a0x*SC;   o[ 2]=a0y*SC;
    o[ 4]=e01x*SC;  o[ 6]=e01y*SC;
    o[ 8]=e12x*SC;  o[10]=e12y*SC;
    o[12]=ib01*ISC2; o[14]=ib12*ISC2; o[16]=ib20*ISC2;
    o[18]=idn*ISC2;
    o[20]=az[0]; o[22]=az[1]; o[24]=az[2];
    o[26]=cr;   o[28]=cg;   o[30]=cb;
}

// block = (64,16): 16 waves. Each wave covers one 16x16 pixel TILE (64 lanes x 4 px,
// quadrant layout) for a 16-face chunk (8 pairs). grid = 256: blockIdx = b*64 + tile.
__launch_bounds__(1024)
__global__ void raster(const float* __restrict__ fd, float* __restrict__ out)
{
    // 80 KB: 16KB face table during loop; 20 reduction arrays [16][64] after (aliased)
    __shared__ float sMEM[20480];

    const int t    = threadIdx.x;      // 0..63
    const int cy   = threadIdx.y;      // 0..15 (face chunk)
    const int bId  = blockIdx.x;       // 0..255
    const int b    = bId >> 6;
    const int tile = bId & 63;
    const int tX = (tile & 7) << 4;
    const int tY = (tile >> 3) << 4;
    const int lx = t & 7, ly = t >> 3;

    // stage the per-batch face table: 4096 floats = 1024 float4, one per thread
    {
        const float4* src = (const float4*)(fd + (b << 12));
        float4* dst = (float4*)sMEM;
        dst[cy*64 + t] = src[cy*64 + t];
    }
    __syncthreads();

    const float SC = 120.11224139682566f;
    const float KGAM = 14.426950408889634f;  // (1/GAMMA)*log2(e)
    const v2f KGH_NEG = { -0.5f*KGAM, -0.5f*KGAM };
    const v2f KGH_POS = {  0.5f*KGAM,  0.5f*KGAM };
    const v2f ONE2 = { 1.0f, 1.0f };
    const v2f EPS2 = { 1e-8f, 1e-8f };

    // 4 pixel coords (scaled space), quadrants of the 16x16 tile
    const float x0 = ((tX + lx + 0.5f) * (1.0f/64.0f) - 1.0f) * SC;
    const float x1 = ((tX + lx + 8.5f) * (1.0f/64.0f) - 1.0f) * SC;
    const float y0 = (1.0f - (tY + ly + 0.5f) * (1.0f/64.0f)) * SC;
    const float y1 = (1.0f - (tY + ly + 8.5f) * (1.0f/64.0f)) * SC;
    const v2f PX0 = { x0, x0 }, PX1 = { x1, x1 };
    const v2f PY0 = { y0, y0 }, PY1 = { y1, y1 };

    const float* fc = sMEM + cy*(8*STR);

    v2f aP0 = ONE2, aS0 = {0,0}, aR00 = {0,0}, aR10 = {0,0}, aR20 = {0,0};
    v2f aP1 = ONE2, aS1 = {0,0}, aR01 = {0,0}, aR11 = {0,0}, aR21 = {0,0};
    v2f aP2 = ONE2, aS2 = {0,0}, aR02 = {0,0}, aR12 = {0,0}, aR22 = {0,0};
    v2f aP3 = ONE2, aS3 = {0,0}, aR03 = {0,0}, aR13 = {0,0}, aR23 = {0,0};

// phase 1: geometry -> barycentrics + signed scaled sq-distance q
#define PH1(J, PXS, PYS)                                                  \
    v2f pa0x##J = PXS - a0x, pa0y##J = PYS - a0y;                         \
    v2f pa1x##J = pa0x##J - e01x, pa1y##J = pa0y##J - e01y;               \
    v2f pa2x##J = pa0x##J + e20x, pa2y##J = pa0y##J + e20y;               \
    v2f b0##J = fma2(-e12y, pa1x##J, e12x*pa1y##J) * idn;                 \
    v2f b1##J = fma2(-e20y, pa2x##J, e20x*pa2y##J) * idn;                 \
    v2f b2##J = fma2(-e01y, pa0x##J, e01x*pa0y##J) * idn;                 \
    v2f q##J;                                                             \
    {                                                                     \
        v2f tt = med01_2(fma2(pa0x##J, g01x, pa0y##J*g01y));              \
        v2f dx = fma2(-tt, e01x, pa0x##J);                                \
        v2f dy = fma2(-tt, e01y, pa0y##J);                                \
        v2f ddA = fma2(dx, dx, dy*dy);                                    \
        tt = med01_2(fma2(pa1x##J, g12x, pa1y##J*g12y));                  \
        dx = fma2(-tt, e12x, pa1x##J);                                    \
        dy = fma2(-tt, e12y, pa1y##J);                                    \
        v2f ddB = fma2(dx, dx, dy*dy);                                    \
        tt = med01_2(fma2(pa2x##J, g20x, pa2y##J*g20y));                  \
        dx = fma2(-tt, e20x, pa2x##J);                                    \
        dy = fma2(-tt, e20y, pa2y##J);                                    \
        v2f ddC = fma2(dx, dx, dy*dy);                                    \
        float ddl = fminf(fminf(ddA.x, ddB.x), ddC.x);                    \
        float ddh = fminf(fminf(ddA.y, ddB.y), ddC.y);                    \
        float mxl = fmaxf(fmaxf(-b0##J.x, -b1##J.x), -b2##J.x);           \
        float mxh = fmaxf(fmaxf(-b0##J.y, -b1##J.y), -b2##J.y);           \
        q##J = (v2f){ copysignf(ddl, mxl), copysignf(ddh, mxh) };         \
    }

// phase 2: sigmoid + softmax-weight accumulation (skippable when tile is far)
#define PH2(J, AP, AS, AR0, AR1, AR2)                                     \
    {                                                                     \
        v2f e2 = { ex2(q##J.x), ex2(q##J.y) };                            \
        v2f den = e2 + ONE2;                                              \
        v2f prob = { rcpf(den.x), rcpf(den.y) };                          \
        AP = fma2(-prob, AP, AP);                                         \
        v2f bc0 = med01_2(b0##J), bc1 = med01_2(b1##J), bc2 = med01_2(b2##J); \
        v2f s = (bc0 + bc1) + (bc2 + EPS2);                               \
        v2f zs = fma2(bc0, z0, fma2(bc1, z1, bc2*z2));                    \
        v2f irs = { rcpf(s.x), rcpf(s.y) };                               \
        v2f zq = fma2(zs*irs, KGH_NEG, KGH_POS);                          \
        v2f ez = { ex2(__builtin_amdgcn_fmed3f(zq.x, 0.0f, KGAM)),        \
                   ex2(__builtin_amdgcn_fmed3f(zq.y, 0.0f, KGAM)) };      \
        v2f wgt = prob * ez;                                              \
        AS = AS + wgt;                                                    \
        AR0 = fma2(wgt, cr, AR0);                                         \
        AR1 = fma2(wgt, cg, AR1);                                         \
        AR2 = fma2(wgt, cb, AR2);                                         \
    }

    for (int i = 0; i < 8; ++i) {
        const float* c = fc + i*STR;
#define LD(k) (*(const v2f*)(c + 2*(k)))
        v2f a0x = LD(0), a0y = LD(1);
        v2f e01x = LD(2), e01y = LD(3);
        v2f e12x = LD(4), e12y = LD(5);
        v2f ib01 = LD(6), ib12 = LD(7), ib20 = LD(8);
        v2f idn = LD(9);
        v2f z0 = LD(10), z1 = LD(11), z2 = LD(12);
        v2f cr = LD(13), cg = LD(14), cb = LD(15);
#undef LD
        v2f e20x = -(e01x + e12x), e20y = -(e01y + e12y);
        v2f g01x = e01x*ib01, g01y = e01y*ib01;
        v2f g12x = e12x*ib12, g12y = e12y*ib12;
        v2f g20x = e20x*ib20, g20y = e20y*ib20;

        PH1(0, PX0, PY0)
        PH1(1, PX1, PY0)
        PH1(2, PX0, PY1)
        PH1(3, PX1, PY1)

        // wave-uniform early-out: whole 16x16 tile far outside both faces
        float qm = fminf(fminf(fminf(q0.x, q0.y), fminf(q1.x, q1.y)),
                         fminf(fminf(q2.x, q2.y), fminf(q3.x, q3.y)));
        if (!__all(qm > 32.0f)) {
            PH2(0, aP0, aS0, aR00, aR10, aR20)
            PH2(1, aP1, aS1, aR01, aR11, aR21)
            PH2(2, aP2, aS2, aR02, aR12, aR22)
            PH2(3, aP3, aS3, aR03, aR13, aR23)
        }
    }
#undef PH1
#undef PH2

    // table reads complete -> alias reduction arrays into the same LDS
    __syncthreads();
    float* red = sMEM;   // [(acc*4 + px)*16 + cy][t]
#define ST(A, J, V) red[(((A)*4 + (J))*16 + cy)*64 + t] = (V);
    ST(0,0, aP0.x*aP0.y)  ST(0,1, aP1.x*aP1.y)  ST(0,2, aP2.x*aP2.y)  ST(0,3, aP3.x*aP3.y)
    ST(1,0, aS0.x+aS0.y)  ST(1,1, aS1.x+aS1.y)  ST(1,2, aS2.x+aS2.y)  ST(1,3, aS3.x+aS3.y)
    ST(2,0, aR00.x+aR00.y) ST(2,1, aR01.x+aR01.y) ST(2,2, aR02.x+aR02.y) ST(2,3, aR03.x+aR03.y)
    ST(3,0, aR10.x+aR10.y) ST(3,1, aR11.x+aR11.y) ST(3,2, aR12.x+aR12.y) ST(3,3, aR13.x+aR13.y)
    ST(4,0, aR20.x+aR20.y) ST(4,1, aR21.x+aR21.y) ST(4,2, aR22.x+aR22.y) ST(4,3, aR23.x+aR23.y)
#undef ST
    __syncthreads();

    if (cy < 4) {
        const int j = cy;
        const int w = tX + lx + (j & 1)*8;
        const int h = tY + ly + (j >> 1)*8;
        const int pix = h*IMG + w;

        float P = 1.0f, St = 0.0f, r0 = 0.0f, r1 = 0.0f, r2 = 0.0f;
#pragma unroll
        for (int c2 = 0; c2 < 16; ++c2) {
            P  *= red[((0*4 + j)*16 + c2)*64 + t];
            St += red[((1*4 + j)*16 + c2)*64 + t];
            r0 += red[((2*4 + j)*16 + c2)*64 + t];
            r1 += red[((3*4 + j)*16 + c2)*64 + t];
            r2 += red[((4*4 + j)*16 + c2)*64 + t];
        }
        float iden = rcpf(St + 1.0f);   // background weight = exp2(0) = 1

        out[b*16384 + pix] = 1.0f - P;
        float* rgb = out + 65536;
        rgb[(b*3 + 0)*16384 + pix] = r0 * iden;
        rgb[(b*3 + 1)*16384 + pix] = r1 * iden;
        rgb[(b*3 + 2)*16384 + pix] = r2 * iden;
    }
}

extern "C" void kernel_launch(void* const* d_in, const int* in_sizes, int n_in,
                              void* d_out, int out_size, void* d_ws, size_t ws_size,
                              hipStream_t stream)
{
    const float* verts  = (const float*)d_in[0];
    const int*   faces  = (const int*)d_in[1];
    const float* colors = (const float*)d_in[2];
    const float* eye    = (const float*)d_in[3];
    float* out = (float*)d_out;
    float* fd  = (float*)d_ws;  // 4*128 pairs * 32 floats = 64 KB

    hipLaunchKernelGGL(prep_faces, dim3(4), dim3(256), 0, stream,
                       verts, faces, colors, eye, fd);
    hipLaunchKernelGGL(raster, dim3(256), dim3(64, 16), 0, stream, fd, out);
}